// Round 11
// baseline (116.922 us; speedup 1.0000x reference)
//
#include <hip/hip_runtime.h>

#define DD 256
#define BB 64
#define SS 256                       // H*W
#define K2 2.8853900817779268f      // 2*log2(e)
#define LOG2E 1.4426950408889634f
#define MAXT 32

#if __has_builtin(__builtin_amdgcn_exp2f)
#define EXP2(x) __builtin_amdgcn_exp2f(x)
#else
#define EXP2(x) exp2f(x)
#endif

static __device__ __forceinline__ float fast_rcp(float x) {
  return __builtin_amdgcn_rcpf(x);
}

// async global->LDS, 16B per lane; LDS dest = wave-uniform base + lane*16
static __device__ __forceinline__ void gload_lds16(const float* g, float* l) {
  __builtin_amdgcn_global_load_lds(
      (const __attribute__((address_space(1))) unsigned int*)(const void*)g,
      (__attribute__((address_space(3))) unsigned int*)(void*)l,
      16, 0, 0);
}

// ---- kernel 1: transpose wv_w into wvT (blocks 0..15) + att_rK = K2*(pe@wo^T+b) ----
__global__ __launch_bounds__(256) void k_prep(
    const float* __restrict__ wv_w,
    const float* __restrict__ wo_w, const float* __restrict__ wo_b,
    float* __restrict__ wvT, float* __restrict__ att_r, int T)
{
  const int tid = threadIdx.x;
  if (blockIdx.x < 16) {
    const int bi = blockIdx.x >> 2;   // d-tile
    const int bj = blockIdx.x & 3;    // c-tile
    __shared__ float tile[64 * 65];
#pragma unroll
    for (int p = 0; p < 4; ++p) {
      int row = p * 16 + (tid >> 4);          // local d
      int col = (tid & 15) * 4;               // local c
      float4 v = *reinterpret_cast<const float4*>(wv_w + (size_t)(bi*64 + row)*DD + bj*64 + col);
      tile[row*65 + col + 0] = v.x;
      tile[row*65 + col + 1] = v.y;
      tile[row*65 + col + 2] = v.z;
      tile[row*65 + col + 3] = v.w;
    }
    __syncthreads();
#pragma unroll
    for (int p = 0; p < 4; ++p) {
      int orow = p * 16 + (tid >> 4);   // local c
      int ocol = (tid & 15) * 4;        // local d
      float4 o;
      o.x = tile[(ocol+0)*65 + orow];
      o.y = tile[(ocol+1)*65 + orow];
      o.z = tile[(ocol+2)*65 + orow];
      o.w = tile[(ocol+3)*65 + orow];
      *reinterpret_cast<float4*>(wvT + (size_t)(bj*64 + orow)*DD + bi*64 + ocol) = o;
    }
    return;
  }
  // ---- att_r branch (pre-scaled by K2) ----
  const int t = blockIdx.x - 16;
  if (t >= T) return;
  __shared__ float pe[DD];
  {
    int i = tid >> 1;
    double r = pow(10000.0, -(double)(2*i) / 256.0);
    double ang = (double)t * r;
    pe[tid] = (float)((tid & 1) ? cos(ang) : sin(ang));
  }
  __syncthreads();
  const float4* wr = reinterpret_cast<const float4*>(wo_w + (size_t)tid * DD);
  const float4* pp = reinterpret_cast<const float4*>(pe);
  float acc = 0.f;
#pragma unroll 8
  for (int k = 0; k < 64; ++k) {
    float4 w4 = wr[k]; float4 p4 = pp[k];
    acc = fmaf(w4.x, p4.x, acc);
    acc = fmaf(w4.y, p4.y, acc);
    acc = fmaf(w4.z, p4.z, acc);
    acc = fmaf(w4.w, p4.w, acc);
  }
  att_r[(size_t)t*DD + tid] = K2 * (acc + wo_b[tid]);
}

// ---- kernel 2 (FUSED): att_x GEMM + raw scores ----
// grid (4 sT, 64 b) = 256 blocks (1/CU, 8 waves/CU), block 512.
// Tile 64s x 256d; thread: wave=tid>>6 owns s = s0+wave*8+j (j=0..7), lane owns d = lane*4..+3.
// acc[8][4] IS att_x after GEMM -> T-loop scores in-register; d-reduce = 6 in-wave shuffles.
// LDS: smem[10240] = wt dbuf (2x16KB) + xs dbuf (2x4KB); overlaid as att_rK[T][256] after GEMM.
__global__ __launch_bounds__(512) void k_attx_score(
    const float* __restrict__ x, const float* __restrict__ wvT,
    const float* __restrict__ wv_b, const float* __restrict__ att_rK,
    const float* __restrict__ we_w,
    float* __restrict__ att_x, float* __restrict__ score, int T)
{
  const int b  = blockIdx.y;
  const int s0 = blockIdx.x * 64;
  const int tid = threadIdx.x;
  const int wave = tid >> 6;           // 0..7
  const int lane = tid & 63;
  const float* xb = x + (size_t)b * DD * SS;   // [c][s]

  __shared__ float smem[10240];        // 40KB: wt[2][4096]@0, xs[2][1024]@8192
  __shared__ float scS[MAXT * 64];     // 8KB raw scores [t][sl]

  float acc[8][4];
#pragma unroll
  for (int j = 0; j < 8; ++j)
#pragma unroll
    for (int r = 0; r < 4; ++r) acc[j][r] = 0.f;

  float4 we4 = *reinterpret_cast<const float4*>(we_w + lane * 4);   // tl-invariant

  // ---- staging geometry ----
  // wt flat = p*2048 + wave*256 + lane*4 -> row p*8+wave (c in chunk), col lane*4 (d)
  const float* wg0 = wvT + (size_t)wave * DD + lane * 4;            // p=0
  const float* wg1 = wvT + (size_t)(8 + wave) * DD + lane * 4;      // p=1
  // xs flat = wave*256 + lane*4 -> row wave*4+(lane>>4), col (lane&15)*4  (waves 0..3)
  const float* xg = xb + (size_t)(wave * 4 + (lane >> 4)) * SS + s0 + (lane & 15) * 4;

#define STAGE(buf, cc_) do {                                                   \
    const size_t woff = (size_t)(cc_) * 16 * DD;                               \
    gload_lds16(wg0 + woff, smem + (buf) * 4096 + wave * 256);                 \
    gload_lds16(wg1 + woff, smem + (buf) * 4096 + 2048 + wave * 256);          \
    if (wave < 4)                                                              \
      gload_lds16(xg + (size_t)(cc_) * 16 * SS,                                \
                  smem + 8192 + (buf) * 1024 + wave * 256);                    \
  } while (0)

  STAGE(0, 0);
  __syncthreads();                       // buf0 ready

  int cur = 0;
  for (int cc = 0; cc < 16; ++cc) {
    if (cc < 15) STAGE(cur ^ 1, cc + 1);   // loads in flight across compute
    const float* wt_c = smem + cur * 4096;
    const float* xs_c = smem + 8192 + cur * 1024;
#pragma unroll
    for (int ci = 0; ci < 16; ++ci) {
      float4 x0 = *reinterpret_cast<const float4*>(xs_c + ci * 64 + wave * 8);      // broadcast
      float4 x1 = *reinterpret_cast<const float4*>(xs_c + ci * 64 + wave * 8 + 4);  // broadcast
      float4 w0 = *reinterpret_cast<const float4*>(wt_c + ci * 256 + lane * 4);     // consecutive
      const float xv[8] = {x0.x, x0.y, x0.z, x0.w, x1.x, x1.y, x1.z, x1.w};
#pragma unroll
      for (int j = 0; j < 8; ++j) {
        acc[j][0] = fmaf(xv[j], w0.x, acc[j][0]);
        acc[j][1] = fmaf(xv[j], w0.y, acc[j][1]);
        acc[j][2] = fmaf(xv[j], w0.z, acc[j][2]);
        acc[j][3] = fmaf(xv[j], w0.w, acc[j][3]);
      }
    }
    __syncthreads();                      // drains staging; next buf ready; buf[cur] reusable
    cur ^= 1;
  }
#undef STAGE

  // ---- bias add, write att_x, scale acc by K2 ----
  {
    float4 bv = *reinterpret_cast<const float4*>(wv_b + lane * 4);
#pragma unroll
    for (int j = 0; j < 8; ++j) {
      float4 o;
      o.x = acc[j][0] + bv.x; o.y = acc[j][1] + bv.y;
      o.z = acc[j][2] + bv.z; o.w = acc[j][3] + bv.w;
      *reinterpret_cast<float4*>(
          att_x + ((size_t)(b * SS + s0 + wave * 8 + j)) * DD + lane * 4) = o;
      acc[j][0] = o.x * K2; acc[j][1] = o.y * K2;
      acc[j][2] = o.z * K2; acc[j][3] = o.w * K2;
    }
  }

  // ---- overlay: stage att_rK (already K2-scaled) into dead staging LDS ----
  for (int idx = tid * 4; idx < T * 256; idx += 2048)
    *reinterpret_cast<float4*>(smem + idx) =
        *reinterpret_cast<const float4*>(att_rK + idx);
  __syncthreads();

  // ---- score phase: sc[t][s] = -2 * sum_d we_d * rcp(exp2(K2*attx + K2*attr) + 1) ----
  for (int t = 0; t < T; ++t) {
    float4 a4 = *reinterpret_cast<const float4*>(smem + t * 256 + lane * 4);  // consecutive b128
#pragma unroll
    for (int j = 0; j < 8; ++j) {
      float p = 0.f;
      p = fmaf(we4.x, fast_rcp(EXP2(acc[j][0] + a4.x) + 1.f), p);
      p = fmaf(we4.y, fast_rcp(EXP2(acc[j][1] + a4.y) + 1.f), p);
      p = fmaf(we4.z, fast_rcp(EXP2(acc[j][2] + a4.z) + 1.f), p);
      p = fmaf(we4.w, fast_rcp(EXP2(acc[j][3] + a4.w) + 1.f), p);
      // reduce over d (all 64 lanes); 8 independent j-chains give ILP
      p += __shfl_xor(p, 1);
      p += __shfl_xor(p, 2);
      p += __shfl_xor(p, 4);
      p += __shfl_xor(p, 8);
      p += __shfl_xor(p, 16);
      p += __shfl_xor(p, 32);
      if (lane == j) scS[t * 64 + wave * 8 + j] = -2.f * p;  // + const (softmax-invariant)
    }
  }
  __syncthreads();
  // coalesced score write: score[b][t][s0+sl]
  for (int idx = tid; idx < T * 64; idx += 512) {
    int t = idx >> 6, sl = idx & 63;
    score[((size_t)b * T + t) * SS + s0 + sl] = scS[idx];
  }
}

// ---- kernel 3 (FUSED): softmax over s + out[b][t][d] = (1/256)*sum_s alpha*att_x ----
// grid (64 b, 4 tg), block 1024: d = tid&255, scg = tid>>8.
__global__ __launch_bounds__(1024) void k_out2(
    const float* __restrict__ att_x, const float* __restrict__ score,
    float* __restrict__ out, int T)
{
  const int b  = blockIdx.x;
  const int tg = blockIdx.y;
  const int tchunk = (T + 3) >> 2;
  const int t0 = tg * tchunk;
  const int nT = (T - t0 < tchunk) ? (T - t0) : tchunk;
  if (nT <= 0) return;
  const int tid = threadIdx.x;
  const int d   = tid & 255;
  const int scg = tid >> 8;   // 0..3
  const int wv4 = (d >> 6);

  __shared__ float al[7 * 256];
  __shared__ float red[4 * 7 * 256];
  __shared__ float mred[8][4];
  __shared__ float sred[8][4];

  for (int idx = tid; idx < 7*256; idx += 1024)
    al[idx] = (idx < nT*256) ? score[((size_t)b*T + t0)*SS + idx] : 0.f;
  __syncthreads();

#pragma unroll
  for (int pass = 0; pass < 2; ++pass) {
    const int r = pass * 4 + scg;       // 0..7
    const bool live = (r < nT);
    float v = live ? al[r * 256 + d] : -3.0e38f;
    float m = v;
    m = fmaxf(m, __shfl_xor(m, 1));
    m = fmaxf(m, __shfl_xor(m, 2));
    m = fmaxf(m, __shfl_xor(m, 4));
    m = fmaxf(m, __shfl_xor(m, 8));
    m = fmaxf(m, __shfl_xor(m, 16));
    m = fmaxf(m, __shfl_xor(m, 32));
    if ((tid & 63) == 0) mred[r][wv4] = m;
    __syncthreads();
    float M = fmaxf(fmaxf(mred[r][0], mred[r][1]), fmaxf(mred[r][2], mred[r][3]));
    float ev = live ? EXP2((v - M) * LOG2E) : 0.f;
    float ss = ev;
    ss += __shfl_xor(ss, 1);
    ss += __shfl_xor(ss, 2);
    ss += __shfl_xor(ss, 4);
    ss += __shfl_xor(ss, 8);
    ss += __shfl_xor(ss, 16);
    ss += __shfl_xor(ss, 32);
    if ((tid & 63) == 0) sred[r][wv4] = ss;
    __syncthreads();
    float S = sred[r][0] + sred[r][1] + sred[r][2] + sred[r][3];
    if (live) al[r * 256 + d] = ev * fast_rcp(S);
  }
  __syncthreads();

  float v[64];
  const float* ax = att_x + ((size_t)(b*SS) + scg*64) * DD + d;
#pragma unroll
  for (int i = 0; i < 64; ++i) v[i] = ax[(size_t)i * DD];

#pragma unroll
  for (int tl = 0; tl < 7; ++tl) {
    float a = 0.f;
#pragma unroll
    for (int i4 = 0; i4 < 16; ++i4) {
      float4 a4 = *reinterpret_cast<const float4*>(&al[tl*256 + scg*64 + i4*4]);  // wave-uniform
      a = fmaf(a4.x, v[i4*4+0], a);
      a = fmaf(a4.y, v[i4*4+1], a);
      a = fmaf(a4.z, v[i4*4+2], a);
      a = fmaf(a4.w, v[i4*4+3], a);
    }
    red[scg*1792 + tl*256 + d] = a;
  }
  __syncthreads();
  for (int idx = tid; idx < nT*256; idx += 1024) {
    float sum = red[idx] + red[1792 + idx] + red[2*1792 + idx] + red[3*1792 + idx];
    out[((size_t)b*T + t0)*SS + idx] = sum * (1.0f/256.0f);
  }
}

extern "C" void kernel_launch(void* const* d_in, const int* in_sizes, int n_in,
                              void* d_out, int out_size, void* d_ws, size_t ws_size,
                              hipStream_t stream) {
  (void)in_sizes; (void)n_in; (void)ws_size;
  const float* x    = (const float*)d_in[0];
  // d_in[1] = seq_len (device int scalar) -- T derived from out_size instead
  const float* wo_w = (const float*)d_in[2];
  const float* wo_b = (const float*)d_in[3];
  const float* wv_w = (const float*)d_in[4];
  const float* wv_b = (const float*)d_in[5];
  const float* we_w = (const float*)d_in[6];
  float* out = (float*)d_out;
  const int T = out_size / (BB * DD);

  float* att_x = (float*)d_ws;                     // 64*256*256 floats (16 MB)
  float* wvT   = att_x + (size_t)BB * SS * DD;     // 65536 floats
  float* att_r = wvT + DD * DD;                    // 64*DD reserved (K2-scaled)
  float* score = att_r + 64 * DD;                  // B*T*256 floats (raw scores)

  k_prep       <<<dim3(16 + T), 256, 0, stream>>>(wv_w, wo_w, wo_b, wvT, att_r, T);
  k_attx_score <<<dim3(4, BB), 512, 0, stream>>>(x, wvT, wv_b, att_r, we_w, att_x, score, T);
  k_out2       <<<dim3(BB, 4), 1024, 0, stream>>>(att_x, score, out, T);
}

// Round 12
// 98.015 us; speedup vs baseline: 1.1929x; 1.1929x over previous
//
#include <hip/hip_runtime.h>

#define DD 256
#define BB 64
#define SS 256                       // H*W
#define K2 2.8853900817779268f      // 2*log2(e)
#define LOG2E 1.4426950408889634f

#if __has_builtin(__builtin_amdgcn_exp2f)
#define EXP2(x) __builtin_amdgcn_exp2f(x)
#else
#define EXP2(x) exp2f(x)
#endif

static __device__ __forceinline__ float fast_rcp(float x) {
  return __builtin_amdgcn_rcpf(x);
}

// ---- kernel 1: transpose wv_w into wvT (blocks 0..15) + att_r = pe@wo^T+b (blocks 16..16+T) ----
__global__ __launch_bounds__(256) void k_prep(
    const float* __restrict__ wv_w,
    const float* __restrict__ wo_w, const float* __restrict__ wo_b,
    float* __restrict__ wvT, float* __restrict__ att_r, int T)
{
  const int tid = threadIdx.x;
  if (blockIdx.x < 16) {
    const int bi = blockIdx.x >> 2;   // d-tile
    const int bj = blockIdx.x & 3;    // c-tile
    __shared__ float tile[64 * 65];
#pragma unroll
    for (int p = 0; p < 4; ++p) {
      int row = p * 16 + (tid >> 4);          // local d
      int col = (tid & 15) * 4;               // local c
      float4 v = *reinterpret_cast<const float4*>(wv_w + (size_t)(bi*64 + row)*DD + bj*64 + col);
      tile[row*65 + col + 0] = v.x;
      tile[row*65 + col + 1] = v.y;
      tile[row*65 + col + 2] = v.z;
      tile[row*65 + col + 3] = v.w;
    }
    __syncthreads();
#pragma unroll
    for (int p = 0; p < 4; ++p) {
      int orow = p * 16 + (tid >> 4);   // local c
      int ocol = (tid & 15) * 4;        // local d
      float4 o;
      o.x = tile[(ocol+0)*65 + orow];
      o.y = tile[(ocol+1)*65 + orow];
      o.z = tile[(ocol+2)*65 + orow];
      o.w = tile[(ocol+3)*65 + orow];
      *reinterpret_cast<float4*>(wvT + (size_t)(bj*64 + orow)*DD + bi*64 + ocol) = o;
    }
    return;
  }
  // ---- att_r branch ----
  const int t = blockIdx.x - 16;
  if (t >= T) return;
  __shared__ float pe[DD];
  {
    int i = tid >> 1;
    double r = pow(10000.0, -(double)(2*i) / 256.0);
    double ang = (double)t * r;
    pe[tid] = (float)((tid & 1) ? cos(ang) : sin(ang));
  }
  __syncthreads();
  const float4* wr = reinterpret_cast<const float4*>(wo_w + (size_t)tid * DD);
  const float4* pp = reinterpret_cast<const float4*>(pe);
  float acc = 0.f;
#pragma unroll 8
  for (int k = 0; k < 64; ++k) {
    float4 w4 = wr[k]; float4 p4 = pp[k];
    acc = fmaf(w4.x, p4.x, acc);
    acc = fmaf(w4.y, p4.y, acc);
    acc = fmaf(w4.z, p4.z, acc);
    acc = fmaf(w4.w, p4.w, acc);
  }
  att_r[(size_t)t*DD + tid] = acc + wo_b[tid];
}

// ---- kernel 2: att_x[b][s][d] = sum_c x[b][c][s] * wvT[c][d] + wv_b[d] ----
// (round-9 champion, byte-identical) grid (4 sT, 2 dT, 64 b), block 256.
// Tile 64s x 128d, thread 8s x 4d; dbuf LDS, one barrier/chunk, reg prefetch.
__global__ __launch_bounds__(256) void k_attx(
    const float* __restrict__ x, const float* __restrict__ wvT,
    const float* __restrict__ wv_b, float* __restrict__ att_x)
{
  const int b  = blockIdx.z;
  const int dT = blockIdx.y;           // 0..1 -> d-half
  const int s0 = blockIdx.x * 64;
  const int tid = threadIdx.x;
  const int sg = tid >> 5;             // 0..7 -> s = s0 + sg*8 + j
  const int dg = tid & 31;             // 0..31 -> d = dT*128 + dg*4
  const float* xb = x + (size_t)b * DD * SS;   // [c][s]

  __shared__ float wt[2][16 * 128];    // 2 x 8 KB   [c][d-local]
  __shared__ float xs[2][16 * 64];     // 2 x 4 KB   [c][s-local]

  float acc[8][4];
#pragma unroll
  for (int j = 0; j < 8; ++j)
#pragma unroll
    for (int r = 0; r < 4; ++r) acc[j][r] = 0.f;

  const float* wsrc0 = wvT + (size_t)(tid >> 5) * DD + dT * 128 + (tid & 31) * 4;
  const float* wsrc1 = wsrc0 + (size_t)8 * DD;
  const float* xsrc = xb + (size_t)(tid >> 4) * SS + s0 + (tid & 15) * 4;

  float4 wA0 = *reinterpret_cast<const float4*>(wsrc0);
  float4 wA1 = *reinterpret_cast<const float4*>(wsrc1);
  float4 xA  = *reinterpret_cast<const float4*>(xsrc);

  int cur = 0;
  for (int cc = 0; cc < 16; ++cc) {
    *reinterpret_cast<float4*>(&wt[cur][tid * 4])        = wA0;
    *reinterpret_cast<float4*>(&wt[cur][1024 + tid * 4]) = wA1;
    *reinterpret_cast<float4*>(&xs[cur][tid * 4])        = xA;
    if (cc < 15) {                                  // prefetch next chunk -> regs
      wA0 = *reinterpret_cast<const float4*>(wsrc0 + (size_t)(cc + 1) * 16 * DD);
      wA1 = *reinterpret_cast<const float4*>(wsrc1 + (size_t)(cc + 1) * 16 * DD);
      xA  = *reinterpret_cast<const float4*>(xsrc  + (size_t)(cc + 1) * 16 * SS);
    }
    __syncthreads();                                // buf[cur] ready
#pragma unroll
    for (int ci = 0; ci < 16; ++ci) {
      float4 x0 = *reinterpret_cast<const float4*>(&xs[cur][ci * 64 + sg * 8]);
      float4 x1 = *reinterpret_cast<const float4*>(&xs[cur][ci * 64 + sg * 8 + 4]);
      float4 w0 = *reinterpret_cast<const float4*>(&wt[cur][ci * 128 + dg * 4]);
      const float xv[8] = {x0.x, x0.y, x0.z, x0.w, x1.x, x1.y, x1.z, x1.w};
#pragma unroll
      for (int j = 0; j < 8; ++j) {
        acc[j][0] = fmaf(xv[j], w0.x, acc[j][0]);
        acc[j][1] = fmaf(xv[j], w0.y, acc[j][1]);
        acc[j][2] = fmaf(xv[j], w0.z, acc[j][2]);
        acc[j][3] = fmaf(xv[j], w0.w, acc[j][3]);
      }
    }
    cur ^= 1;
  }

  float4 bv = *reinterpret_cast<const float4*>(wv_b + dT * 128 + dg * 4);
#pragma unroll
  for (int j = 0; j < 8; ++j) {
    float4 o;
    o.x = acc[j][0] + bv.x; o.y = acc[j][1] + bv.y;
    o.z = acc[j][2] + bv.z; o.w = acc[j][3] + bv.w;
    float* dst = att_x + ((size_t)(b * SS + s0 + sg * 8 + j)) * DD + dT * 128 + dg * 4;
    *reinterpret_cast<float4*>(dst) = o;
  }
}

// ---- kernel 3 (MERGED): scores + softmax + out for a (b, t-quarter) block ----
// grid (64 b, 4 tq) = 256 blocks (1/CU, 16 waves), block 1024.
// Phase A: thread (s=tid>>2, c=tid&3) holds K2*att_x[b][s][c*64..+63] in 16 float4 regs;
//          per t: 16 TERMs + 2-shuffle c-reduce -> scS LDS.  No global score round-trip.
// Softmax on scS rows; Phase B: k_out2's weighted sum (regs reused for v[64]).
#define SC(F) do { F.x *= K2; F.y *= K2; F.z *= K2; F.w *= K2; } while (0)
#define TERM(F, KK) do {                                                   \
    float4 a4 = *reinterpret_cast<const float4*>(aS + (KK) * 4);           \
    float4 w4 = *reinterpret_cast<const float4*>(wS + (KK) * 4);           \
    p = fmaf(w4.x, fast_rcp(EXP2(F.x + a4.x) + 1.f), p);                   \
    p = fmaf(w4.y, fast_rcp(EXP2(F.y + a4.y) + 1.f), p);                   \
    p = fmaf(w4.z, fast_rcp(EXP2(F.z + a4.z) + 1.f), p);                   \
    p = fmaf(w4.w, fast_rcp(EXP2(F.w + a4.w) + 1.f), p);                   \
  } while (0)

__global__ __launch_bounds__(1024, 4) void k_score_out(
    const float* __restrict__ att_x, const float* __restrict__ att_r,
    const float* __restrict__ we_w, float* __restrict__ out, int T)
{
  const int b  = blockIdx.x;
  const int tq = blockIdx.y;
  const int tchunk = (T + 3) >> 2;      // <= 8
  const int t0 = tq * tchunk;
  const int nT = (T - t0 < tchunk) ? (T - t0) : tchunk;
  if (nT <= 0) return;
  const int tid = threadIdx.x;

  __shared__ float attrS[8][272];       // [tl][c*68 + j] quarter-major +4 pad
  __shared__ float weS[272];
  __shared__ float scS[8 * 256];        // scores -> alpha (in place)
  __shared__ float red[4 * 8 * 256];    // 32 KB out-reduce
  __shared__ float mred[8][4];
  __shared__ float sred[8][4];

  // ---- stage att_r*K2 (padded), we (padded), zero scS ----
  if (tid < 256) weS[(tid >> 6) * 68 + (tid & 63)] = we_w[tid];
  for (int idx = tid; idx < nT * 256; idx += 1024) {
    int tl = idx >> 8, d = idx & 255;
    attrS[tl][(d >> 6) * 68 + (d & 63)] = att_r[(size_t)(t0 + tl) * DD + d] * K2;
  }
  for (int idx = tid; idx < 8 * 256; idx += 1024) scS[idx] = 0.f;

  // ---- frag: 16 named float4 (64 VGPR), K2-scaled ----
  const int s = tid >> 2;
  const int c = tid & 3;
  float4 f0, f1, f2, f3, f4, f5, f6, f7, f8, f9, f10, f11, f12, f13, f14, f15;
  {
    const float4* ax4 = reinterpret_cast<const float4*>(
        att_x + ((size_t)(b * SS + s)) * DD + c * 64);
    f0 = ax4[0];  f1 = ax4[1];  f2 = ax4[2];  f3 = ax4[3];
    f4 = ax4[4];  f5 = ax4[5];  f6 = ax4[6];  f7 = ax4[7];
    f8 = ax4[8];  f9 = ax4[9];  f10 = ax4[10]; f11 = ax4[11];
    f12 = ax4[12]; f13 = ax4[13]; f14 = ax4[14]; f15 = ax4[15];
    SC(f0); SC(f1); SC(f2); SC(f3); SC(f4); SC(f5); SC(f6); SC(f7);
    SC(f8); SC(f9); SC(f10); SC(f11); SC(f12); SC(f13); SC(f14); SC(f15);
  }
  __syncthreads();

  // ---- Phase A: raw scores ----
  for (int tl = 0; tl < nT; ++tl) {
    const float* aS = &attrS[tl][c * 68];
    const float* wS = &weS[c * 68];
    float p = 0.f;
    TERM(f0, 0);  TERM(f1, 1);  TERM(f2, 2);  TERM(f3, 3);
    TERM(f4, 4);  TERM(f5, 5);  TERM(f6, 6);  TERM(f7, 7);
    TERM(f8, 8);  TERM(f9, 9);  TERM(f10, 10); TERM(f11, 11);
    TERM(f12, 12); TERM(f13, 13); TERM(f14, 14); TERM(f15, 15);
    p += __shfl_xor(p, 1);
    p += __shfl_xor(p, 2);
    if (c == 0) scS[tl * 256 + s] = -2.f * p;   // + softmax-invariant const (dropped)
  }
  __syncthreads();

  // ---- softmax over s for each live row (in LDS) ----
  const int d   = tid & 255;
  const int scg = tid >> 8;   // 0..3
  const int wv4 = d >> 6;
#pragma unroll
  for (int pass = 0; pass < 2; ++pass) {
    const int r = pass * 4 + scg;       // 0..7
    const bool live = (r < nT);
    float v = live ? scS[r * 256 + d] : -3.0e38f;
    float m = v;
    m = fmaxf(m, __shfl_xor(m, 1));
    m = fmaxf(m, __shfl_xor(m, 2));
    m = fmaxf(m, __shfl_xor(m, 4));
    m = fmaxf(m, __shfl_xor(m, 8));
    m = fmaxf(m, __shfl_xor(m, 16));
    m = fmaxf(m, __shfl_xor(m, 32));
    if ((tid & 63) == 0) mred[r][wv4] = m;
    __syncthreads();
    float M = fmaxf(fmaxf(mred[r][0], mred[r][1]), fmaxf(mred[r][2], mred[r][3]));
    float ev = live ? EXP2((v - M) * LOG2E) : 0.f;
    float ss = ev;
    ss += __shfl_xor(ss, 1);
    ss += __shfl_xor(ss, 2);
    ss += __shfl_xor(ss, 4);
    ss += __shfl_xor(ss, 8);
    ss += __shfl_xor(ss, 16);
    ss += __shfl_xor(ss, 32);
    if ((tid & 63) == 0) sred[r][wv4] = ss;
    __syncthreads();
    float S = sred[r][0] + sred[r][1] + sred[r][2] + sred[r][3];
    if (live) scS[r * 256 + d] = ev * fast_rcp(S);
  }
  __syncthreads();

  // ---- Phase B: out[b][t][d] = (1/256) * sum_s alpha * att_x[b][s][d] ----
  float v[64];
  const float* ax = att_x + ((size_t)(b * SS) + scg * 64) * DD + d;
#pragma unroll
  for (int i = 0; i < 64; ++i) v[i] = ax[(size_t)i * DD];

#pragma unroll
  for (int tl = 0; tl < 8; ++tl) {
    float a = 0.f;
#pragma unroll
    for (int i4 = 0; i4 < 16; ++i4) {
      float4 a4 = *reinterpret_cast<const float4*>(&scS[tl*256 + scg*64 + i4*4]);  // wave-uniform
      a = fmaf(a4.x, v[i4*4+0], a);
      a = fmaf(a4.y, v[i4*4+1], a);
      a = fmaf(a4.z, v[i4*4+2], a);
      a = fmaf(a4.w, v[i4*4+3], a);
    }
    red[scg * 2048 + tl * 256 + d] = a;
  }
  __syncthreads();
  for (int idx = tid; idx < nT * 256; idx += 1024) {
    float sum = red[idx] + red[2048 + idx] + red[2*2048 + idx] + red[3*2048 + idx];
    out[((size_t)b * T + t0) * SS + idx] = sum * (1.0f / 256.0f);
  }
}

extern "C" void kernel_launch(void* const* d_in, const int* in_sizes, int n_in,
                              void* d_out, int out_size, void* d_ws, size_t ws_size,
                              hipStream_t stream) {
  (void)in_sizes; (void)n_in; (void)ws_size;
  const float* x    = (const float*)d_in[0];
  // d_in[1] = seq_len (device int scalar) -- T derived from out_size instead
  const float* wo_w = (const float*)d_in[2];
  const float* wo_b = (const float*)d_in[3];
  const float* wv_w = (const float*)d_in[4];
  const float* wv_b = (const float*)d_in[5];
  const float* we_w = (const float*)d_in[6];
  float* out = (float*)d_out;
  const int T = out_size / (BB * DD);

  float* att_x = (float*)d_ws;                     // 64*256*256 floats (16 MB)
  float* wvT   = att_x + (size_t)BB * SS * DD;     // 65536 floats
  float* att_r = wvT + DD * DD;                    // 64*DD reserved

  k_prep      <<<dim3(16 + T), 256, 0, stream>>>(wv_w, wo_w, wo_b, wvT, att_r, T);
  k_attx      <<<dim3(4, 2, BB), 256, 0, stream>>>(x, wvT, wv_b, att_x);
  k_score_out <<<dim3(BB, 4), 1024, 0, stream>>>(att_x, att_r, we_w, out, T);
}

// Round 13
// 94.829 us; speedup vs baseline: 1.2330x; 1.0336x over previous
//
#include <hip/hip_runtime.h>

#define DD 256
#define BB 64
#define SS 256                       // H*W
#define K2 2.8853900817779268f      // 2*log2(e)
#define LOG2E 1.4426950408889634f
#define MAXT 32

#if __has_builtin(__builtin_amdgcn_exp2f)
#define EXP2(x) __builtin_amdgcn_exp2f(x)
#else
#define EXP2(x) exp2f(x)
#endif

static __device__ __forceinline__ float fast_rcp(float x) {
  return __builtin_amdgcn_rcpf(x);
}

// ---- kernel 1: transpose wv_w into wvT (blocks 0..15) + att_r = pe@wo^T+b (blocks 16..16+T) ----
__global__ __launch_bounds__(256) void k_prep(
    const float* __restrict__ wv_w,
    const float* __restrict__ wo_w, const float* __restrict__ wo_b,
    float* __restrict__ wvT, float* __restrict__ att_r, int T)
{
  const int tid = threadIdx.x;
  if (blockIdx.x < 16) {
    const int bi = blockIdx.x >> 2;   // d-tile
    const int bj = blockIdx.x & 3;    // c-tile
    __shared__ float tile[64 * 65];
#pragma unroll
    for (int p = 0; p < 4; ++p) {
      int row = p * 16 + (tid >> 4);          // local d
      int col = (tid & 15) * 4;               // local c
      float4 v = *reinterpret_cast<const float4*>(wv_w + (size_t)(bi*64 + row)*DD + bj*64 + col);
      tile[row*65 + col + 0] = v.x;
      tile[row*65 + col + 1] = v.y;
      tile[row*65 + col + 2] = v.z;
      tile[row*65 + col + 3] = v.w;
    }
    __syncthreads();
#pragma unroll
    for (int p = 0; p < 4; ++p) {
      int orow = p * 16 + (tid >> 4);   // local c
      int ocol = (tid & 15) * 4;        // local d
      float4 o;
      o.x = tile[(ocol+0)*65 + orow];
      o.y = tile[(ocol+1)*65 + orow];
      o.z = tile[(ocol+2)*65 + orow];
      o.w = tile[(ocol+3)*65 + orow];
      *reinterpret_cast<float4*>(wvT + (size_t)(bj*64 + orow)*DD + bi*64 + ocol) = o;
    }
    return;
  }
  // ---- att_r branch ----
  const int t = blockIdx.x - 16;
  if (t >= T) return;
  __shared__ float pe[DD];
  {
    int i = tid >> 1;
    double r = pow(10000.0, -(double)(2*i) / 256.0);
    double ang = (double)t * r;
    pe[tid] = (float)((tid & 1) ? cos(ang) : sin(ang));
  }
  __syncthreads();
  const float4* wr = reinterpret_cast<const float4*>(wo_w + (size_t)tid * DD);
  const float4* pp = reinterpret_cast<const float4*>(pe);
  float acc = 0.f;
#pragma unroll 8
  for (int k = 0; k < 64; ++k) {
    float4 w4 = wr[k]; float4 p4 = pp[k];
    acc = fmaf(w4.x, p4.x, acc);
    acc = fmaf(w4.y, p4.y, acc);
    acc = fmaf(w4.z, p4.z, acc);
    acc = fmaf(w4.w, p4.w, acc);
  }
  att_r[(size_t)t*DD + tid] = acc + wo_b[tid];
}

// ---- kernel 2: att_x[b][s][d] = sum_c x[b][c][s] * wvT[c][d] + wv_b[d] ----
// grid (4 sT, 64 b, 2 dT), block 256. Tile 64s x 128d, thread 8s x 4d.
// CK=32 (8 chunks, 8 barriers); dbuf LDS 48 KB; reg prefetch, ONE barrier/chunk.
// dT-pair 256 apart in linear id -> same XCD -> x[b] slice HBM-fetched once.
__global__ __launch_bounds__(256) void k_attx(
    const float* __restrict__ x, const float* __restrict__ wvT,
    const float* __restrict__ wv_b, float* __restrict__ att_x)
{
  const int b  = blockIdx.y;
  const int dT = blockIdx.z;           // 0..1 -> d-half
  const int s0 = blockIdx.x * 64;
  const int tid = threadIdx.x;
  const int sg = tid >> 5;             // 0..7 -> s = s0 + sg*8 + j
  const int dg = tid & 31;             // 0..31 -> d = dT*128 + dg*4
  const float* xb = x + (size_t)b * DD * SS;   // [c][s]

  __shared__ float wt[2][32 * 128];    // 2 x 16 KB  [c][d-local]
  __shared__ float xs[2][32 * 64];     // 2 x 8 KB   [c][s-local]

  float acc[8][4];
#pragma unroll
  for (int j = 0; j < 8; ++j)
#pragma unroll
    for (int r = 0; r < 4; ++r) acc[j][r] = 0.f;

  // staging (flat, coalesced, lane-consecutive LDS writes)
  // wt flat[tid*4 + k*1024] <- wvT[cc*32 + (tid>>5) + 8k][dT*128 + (tid&31)*4], k=0..3
  const float* wsrc = wvT + (size_t)(tid >> 5) * DD + dT * 128 + (tid & 31) * 4;
  // xs flat[tid*4 + k*1024] <- x[b][cc*32 + (tid>>4) + 16k][s0 + (tid&15)*4], k=0..1
  const float* xsrc = xb + (size_t)(tid >> 4) * SS + s0 + (tid & 15) * 4;

  float4 wA[4], xA[2];
#pragma unroll
  for (int k = 0; k < 4; ++k)
    wA[k] = *reinterpret_cast<const float4*>(wsrc + (size_t)(8 * k) * DD);
#pragma unroll
  for (int k = 0; k < 2; ++k)
    xA[k] = *reinterpret_cast<const float4*>(xsrc + (size_t)(16 * k) * SS);

  int cur = 0;
  for (int cc = 0; cc < 8; ++cc) {
#pragma unroll
    for (int k = 0; k < 4; ++k)
      *reinterpret_cast<float4*>(&wt[cur][tid * 4 + k * 1024]) = wA[k];
#pragma unroll
    for (int k = 0; k < 2; ++k)
      *reinterpret_cast<float4*>(&xs[cur][tid * 4 + k * 1024]) = xA[k];
    if (cc < 7) {                                   // prefetch next chunk -> regs
#pragma unroll
      for (int k = 0; k < 4; ++k)
        wA[k] = *reinterpret_cast<const float4*>(wsrc + (size_t)(32 * (cc + 1) + 8 * k) * DD);
#pragma unroll
      for (int k = 0; k < 2; ++k)
        xA[k] = *reinterpret_cast<const float4*>(xsrc + (size_t)(32 * (cc + 1) + 16 * k) * SS);
    }
    __syncthreads();                                // buf[cur] ready
#pragma unroll
    for (int ci = 0; ci < 32; ++ci) {
      float4 x0 = *reinterpret_cast<const float4*>(&xs[cur][ci * 64 + sg * 8]);      // broadcast
      float4 x1 = *reinterpret_cast<const float4*>(&xs[cur][ci * 64 + sg * 8 + 4]);  // broadcast
      float4 w0 = *reinterpret_cast<const float4*>(&wt[cur][ci * 128 + dg * 4]);     // consecutive
      const float xv[8] = {x0.x, x0.y, x0.z, x0.w, x1.x, x1.y, x1.z, x1.w};
#pragma unroll
      for (int j = 0; j < 8; ++j) {
        acc[j][0] = fmaf(xv[j], w0.x, acc[j][0]);
        acc[j][1] = fmaf(xv[j], w0.y, acc[j][1]);
        acc[j][2] = fmaf(xv[j], w0.z, acc[j][2]);
        acc[j][3] = fmaf(xv[j], w0.w, acc[j][3]);
      }
    }
    cur ^= 1;   // buf rewritten 2 iterations later, after an intervening barrier
  }

  float4 bv = *reinterpret_cast<const float4*>(wv_b + dT * 128 + dg * 4);
#pragma unroll
  for (int j = 0; j < 8; ++j) {
    float4 o;
    o.x = acc[j][0] + bv.x; o.y = acc[j][1] + bv.y;
    o.z = acc[j][2] + bv.z; o.w = acc[j][3] + bv.w;
    float* dst = att_x + ((size_t)(b * SS + s0 + sg * 8 + j)) * DD + dT * 128 + dg * 4;
    *reinterpret_cast<float4*>(dst) = o;
  }
}

// ---- kernel 3: raw scores (no softmax).  grid (4 s-tiles of 64, 64 b), block 1024. ----
// thread: s = tid>>4 (64 s/block), c = tid&15 owns d in [c*16, c*16+16).
__global__ __launch_bounds__(1024) void k_score2(
    const float* __restrict__ att_x, const float* __restrict__ att_r,
    const float* __restrict__ we_w, float* __restrict__ score, int T)
{
  const int b  = blockIdx.y;
  const int s0 = blockIdx.x * 64;
  const int tid = threadIdx.x;
  const int s  = tid >> 4;       // 0..63
  const int c  = tid & 15;       // 0..15

  __shared__ float attrS[MAXT * 320];   // [t][c*20 + j], c-stride 20: 2-way bank alias (free)
  __shared__ float scS[MAXT * 64];

  float f0x, f0y, f0z, f0w, f1x, f1y, f1z, f1w;
  float f2x, f2y, f2z, f2w, f3x, f3y, f3z, f3w;
  {
    const float4* ax4 = reinterpret_cast<const float4*>(
        att_x + ((size_t)(b * SS + s0 + s)) * DD + c * 16);
    float4 a = ax4[0], bq = ax4[1], cq = ax4[2], dq = ax4[3];
    f0x = a.x*K2;  f0y = a.y*K2;  f0z = a.z*K2;  f0w = a.w*K2;
    f1x = bq.x*K2; f1y = bq.y*K2; f1z = bq.z*K2; f1w = bq.w*K2;
    f2x = cq.x*K2; f2y = cq.y*K2; f2z = cq.z*K2; f2w = cq.w*K2;
    f3x = dq.x*K2; f3y = dq.y*K2; f3z = dq.z*K2; f3w = dq.w*K2;
  }
  float4 w0, w1, w2, w3;
  {
    const float4* we4 = reinterpret_cast<const float4*>(we_w + c * 16);
    w0 = we4[0]; w1 = we4[1]; w2 = we4[2]; w3 = we4[3];
  }
  for (int idx = tid; idx < T * 256; idx += 1024) {
    int t = idx >> 8, d = idx & 255;
    attrS[t * 320 + (d >> 4) * 20 + (d & 15)] = att_r[(size_t)t * DD + d] * K2;
  }
  __syncthreads();

  for (int tl = 0; tl < T; ++tl) {
    const float* aS = &attrS[tl * 320 + c * 20];
    float4 a0 = *reinterpret_cast<const float4*>(aS);
    float4 a1 = *reinterpret_cast<const float4*>(aS + 4);
    float4 a2 = *reinterpret_cast<const float4*>(aS + 8);
    float4 a3 = *reinterpret_cast<const float4*>(aS + 12);
    float part = 0.f;
    part = fmaf(w0.x, fast_rcp(EXP2(f0x + a0.x) + 1.f), part);
    part = fmaf(w0.y, fast_rcp(EXP2(f0y + a0.y) + 1.f), part);
    part = fmaf(w0.z, fast_rcp(EXP2(f0z + a0.z) + 1.f), part);
    part = fmaf(w0.w, fast_rcp(EXP2(f0w + a0.w) + 1.f), part);
    part = fmaf(w1.x, fast_rcp(EXP2(f1x + a1.x) + 1.f), part);
    part = fmaf(w1.y, fast_rcp(EXP2(f1y + a1.y) + 1.f), part);
    part = fmaf(w1.z, fast_rcp(EXP2(f1z + a1.z) + 1.f), part);
    part = fmaf(w1.w, fast_rcp(EXP2(f1w + a1.w) + 1.f), part);
    part = fmaf(w2.x, fast_rcp(EXP2(f2x + a2.x) + 1.f), part);
    part = fmaf(w2.y, fast_rcp(EXP2(f2y + a2.y) + 1.f), part);
    part = fmaf(w2.z, fast_rcp(EXP2(f2z + a2.z) + 1.f), part);
    part = fmaf(w2.w, fast_rcp(EXP2(f2w + a2.w) + 1.f), part);
    part = fmaf(w3.x, fast_rcp(EXP2(f3x + a3.x) + 1.f), part);
    part = fmaf(w3.y, fast_rcp(EXP2(f3y + a3.y) + 1.f), part);
    part = fmaf(w3.z, fast_rcp(EXP2(f3z + a3.z) + 1.f), part);
    part = fmaf(w3.w, fast_rcp(EXP2(f3w + a3.w) + 1.f), part);
    part += __shfl_xor(part, 1);
    part += __shfl_xor(part, 2);
    part += __shfl_xor(part, 4);
    part += __shfl_xor(part, 8);
    if (c == 0) scS[tl * 64 + s] = -2.f * part;   // + softmax-invariant const (dropped)
  }
  __syncthreads();
  for (int idx = tid; idx < T * 64; idx += 1024) {
    int t = idx >> 6, sl = idx & 63;
    score[((size_t)b * T + t) * SS + s0 + sl] = scS[idx];
  }
}

// ---- kernel 4 (FUSED): softmax over s + out[b][t][d] = (1/256)*sum_s alpha*att_x ----
// grid (64 b, 4 tg), block 1024: d = tid&255, scg = tid>>8.
__global__ __launch_bounds__(1024) void k_out2(
    const float* __restrict__ att_x, const float* __restrict__ score,
    float* __restrict__ out, int T)
{
  const int b  = blockIdx.x;
  const int tg = blockIdx.y;
  const int tchunk = (T + 3) >> 2;
  const int t0 = tg * tchunk;
  const int nT = (T - t0 < tchunk) ? (T - t0) : tchunk;
  if (nT <= 0) return;
  const int tid = threadIdx.x;
  const int d   = tid & 255;
  const int scg = tid >> 8;   // 0..3
  const int wv4 = (d >> 6);

  __shared__ float al[7 * 256];
  __shared__ float red[4 * 7 * 256];
  __shared__ float mred[8][4];
  __shared__ float sred[8][4];

  for (int idx = tid; idx < 7*256; idx += 1024)
    al[idx] = (idx < nT*256) ? score[((size_t)b*T + t0)*SS + idx] : 0.f;
  __syncthreads();

#pragma unroll
  for (int pass = 0; pass < 2; ++pass) {
    const int r = pass * 4 + scg;       // 0..7
    const bool live = (r < nT);
    float v = live ? al[r * 256 + d] : -3.0e38f;
    float m = v;
    m = fmaxf(m, __shfl_xor(m, 1));
    m = fmaxf(m, __shfl_xor(m, 2));
    m = fmaxf(m, __shfl_xor(m, 4));
    m = fmaxf(m, __shfl_xor(m, 8));
    m = fmaxf(m, __shfl_xor(m, 16));
    m = fmaxf(m, __shfl_xor(m, 32));
    if ((tid & 63) == 0) mred[r][wv4] = m;
    __syncthreads();
    float M = fmaxf(fmaxf(mred[r][0], mred[r][1]), fmaxf(mred[r][2], mred[r][3]));
    float ev = live ? EXP2((v - M) * LOG2E) : 0.f;
    float ss = ev;
    ss += __shfl_xor(ss, 1);
    ss += __shfl_xor(ss, 2);
    ss += __shfl_xor(ss, 4);
    ss += __shfl_xor(ss, 8);
    ss += __shfl_xor(ss, 16);
    ss += __shfl_xor(ss, 32);
    if ((tid & 63) == 0) sred[r][wv4] = ss;
    __syncthreads();
    float S = sred[r][0] + sred[r][1] + sred[r][2] + sred[r][3];
    if (live) al[r * 256 + d] = ev * fast_rcp(S);
  }
  __syncthreads();

  float v[64];
  const float* ax = att_x + ((size_t)(b*SS) + scg*64) * DD + d;
#pragma unroll
  for (int i = 0; i < 64; ++i) v[i] = ax[(size_t)i * DD];

#pragma unroll
  for (int tl = 0; tl < 7; ++tl) {
    float a = 0.f;
#pragma unroll
    for (int i4 = 0; i4 < 16; ++i4) {
      float4 a4 = *reinterpret_cast<const float4*>(&al[tl*256 + scg*64 + i4*4]);  // wave-uniform
      a = fmaf(a4.x, v[i4*4+0], a);
      a = fmaf(a4.y, v[i4*4+1], a);
      a = fmaf(a4.z, v[i4*4+2], a);
      a = fmaf(a4.w, v[i4*4+3], a);
    }
    red[scg*1792 + tl*256 + d] = a;
  }
  __syncthreads();
  for (int idx = tid; idx < nT*256; idx += 1024) {
    float sum = red[idx] + red[1792 + idx] + red[2*1792 + idx] + red[3*1792 + idx];
    out[((size_t)b*T + t0)*SS + idx] = sum * (1.0f/256.0f);
  }
}

extern "C" void kernel_launch(void* const* d_in, const int* in_sizes, int n_in,
                              void* d_out, int out_size, void* d_ws, size_t ws_size,
                              hipStream_t stream) {
  (void)in_sizes; (void)n_in; (void)ws_size;
  const float* x    = (const float*)d_in[0];
  // d_in[1] = seq_len (device int scalar) -- T derived from out_size instead
  const float* wo_w = (const float*)d_in[2];
  const float* wo_b = (const float*)d_in[3];
  const float* wv_w = (const float*)d_in[4];
  const float* wv_b = (const float*)d_in[5];
  const float* we_w = (const float*)d_in[6];
  float* out = (float*)d_out;
  const int T = out_size / (BB * DD);

  float* att_x = (float*)d_ws;                     // 64*256*256 floats (16 MB)
  float* wvT   = att_x + (size_t)BB * SS * DD;     // 65536 floats
  float* att_r = wvT + DD * DD;                    // 64*DD reserved
  float* score = att_r + 64 * DD;                  // B*T*256 floats (raw scores)

  k_prep   <<<dim3(16 + T), 256, 0, stream>>>(wv_w, wo_w, wo_b, wvT, att_r, T);
  k_attx   <<<dim3(4, BB, 2), 256, 0, stream>>>(x, wvT, wv_b, att_x);
  k_score2 <<<dim3(4, BB), 1024, 0, stream>>>(att_x, att_r, we_w, score, T);
  k_out2   <<<dim3(BB, 4), 1024, 0, stream>>>(att_x, score, out, T);
}

// Round 14
// 80.895 us; speedup vs baseline: 1.4454x; 1.1723x over previous
//
#include <hip/hip_runtime.h>

#define DD 256
#define BB 64
#define SS 256                       // H*W
#define K2 2.8853900817779268f      // 2*log2(e)
#define LOG2E 1.4426950408889634f

#if __has_builtin(__builtin_amdgcn_exp2f)
#define EXP2(x) __builtin_amdgcn_exp2f(x)
#else
#define EXP2(x) exp2f(x)
#endif

static __device__ __forceinline__ float fast_rcp(float x) {
  return __builtin_amdgcn_rcpf(x);
}

// ---- kernel 1: transpose wv_w into wvT (blocks 0..15) + att_r = pe@wo^T+b (blocks 16..16+T) ----
__global__ __launch_bounds__(256) void k_prep(
    const float* __restrict__ wv_w,
    const float* __restrict__ wo_w, const float* __restrict__ wo_b,
    float* __restrict__ wvT, float* __restrict__ att_r, int T)
{
  const int tid = threadIdx.x;
  if (blockIdx.x < 16) {
    const int bi = blockIdx.x >> 2;   // d-tile
    const int bj = blockIdx.x & 3;    // c-tile
    __shared__ float tile[64 * 65];
#pragma unroll
    for (int p = 0; p < 4; ++p) {
      int row = p * 16 + (tid >> 4);          // local d
      int col = (tid & 15) * 4;               // local c
      float4 v = *reinterpret_cast<const float4*>(wv_w + (size_t)(bi*64 + row)*DD + bj*64 + col);
      tile[row*65 + col + 0] = v.x;
      tile[row*65 + col + 1] = v.y;
      tile[row*65 + col + 2] = v.z;
      tile[row*65 + col + 3] = v.w;
    }
    __syncthreads();
#pragma unroll
    for (int p = 0; p < 4; ++p) {
      int orow = p * 16 + (tid >> 4);   // local c
      int ocol = (tid & 15) * 4;        // local d
      float4 o;
      o.x = tile[(ocol+0)*65 + orow];
      o.y = tile[(ocol+1)*65 + orow];
      o.z = tile[(ocol+2)*65 + orow];
      o.w = tile[(ocol+3)*65 + orow];
      *reinterpret_cast<float4*>(wvT + (size_t)(bj*64 + orow)*DD + bi*64 + ocol) = o;
    }
    return;
  }
  // ---- att_r branch ----
  const int t = blockIdx.x - 16;
  if (t >= T) return;
  __shared__ float pe[DD];
  {
    int i = tid >> 1;
    double r = pow(10000.0, -(double)(2*i) / 256.0);
    double ang = (double)t * r;
    pe[tid] = (float)((tid & 1) ? cos(ang) : sin(ang));
  }
  __syncthreads();
  const float4* wr = reinterpret_cast<const float4*>(wo_w + (size_t)tid * DD);
  const float4* pp = reinterpret_cast<const float4*>(pe);
  float acc = 0.f;
#pragma unroll 8
  for (int k = 0; k < 64; ++k) {
    float4 w4 = wr[k]; float4 p4 = pp[k];
    acc = fmaf(w4.x, p4.x, acc);
    acc = fmaf(w4.y, p4.y, acc);
    acc = fmaf(w4.z, p4.z, acc);
    acc = fmaf(w4.w, p4.w, acc);
  }
  att_r[(size_t)t*DD + tid] = acc + wo_b[tid];
}

// ---- kernel 2: att_x[b][s][d] = sum_c x[b][c][s] * wvT[c][d] + wv_b[d] ----
// (round-9 champion, byte-identical) grid (4 sT, 2 dT, 64 b), block 256.
// Tile 64s x 128d, thread 8s x 4d; dbuf LDS, one barrier/chunk, reg prefetch.
__global__ __launch_bounds__(256) void k_attx(
    const float* __restrict__ x, const float* __restrict__ wvT,
    const float* __restrict__ wv_b, float* __restrict__ att_x)
{
  const int b  = blockIdx.z;
  const int dT = blockIdx.y;           // 0..1 -> d-half
  const int s0 = blockIdx.x * 64;
  const int tid = threadIdx.x;
  const int sg = tid >> 5;             // 0..7 -> s = s0 + sg*8 + j
  const int dg = tid & 31;             // 0..31 -> d = dT*128 + dg*4
  const float* xb = x + (size_t)b * DD * SS;   // [c][s]

  __shared__ float wt[2][16 * 128];    // 2 x 8 KB   [c][d-local]
  __shared__ float xs[2][16 * 64];     // 2 x 4 KB   [c][s-local]

  float acc[8][4];
#pragma unroll
  for (int j = 0; j < 8; ++j)
#pragma unroll
    for (int r = 0; r < 4; ++r) acc[j][r] = 0.f;

  const float* wsrc0 = wvT + (size_t)(tid >> 5) * DD + dT * 128 + (tid & 31) * 4;
  const float* wsrc1 = wsrc0 + (size_t)8 * DD;
  const float* xsrc = xb + (size_t)(tid >> 4) * SS + s0 + (tid & 15) * 4;

  float4 wA0 = *reinterpret_cast<const float4*>(wsrc0);
  float4 wA1 = *reinterpret_cast<const float4*>(wsrc1);
  float4 xA  = *reinterpret_cast<const float4*>(xsrc);

  int cur = 0;
  for (int cc = 0; cc < 16; ++cc) {
    *reinterpret_cast<float4*>(&wt[cur][tid * 4])        = wA0;
    *reinterpret_cast<float4*>(&wt[cur][1024 + tid * 4]) = wA1;
    *reinterpret_cast<float4*>(&xs[cur][tid * 4])        = xA;
    if (cc < 15) {                                  // prefetch next chunk -> regs
      wA0 = *reinterpret_cast<const float4*>(wsrc0 + (size_t)(cc + 1) * 16 * DD);
      wA1 = *reinterpret_cast<const float4*>(wsrc1 + (size_t)(cc + 1) * 16 * DD);
      xA  = *reinterpret_cast<const float4*>(xsrc  + (size_t)(cc + 1) * 16 * SS);
    }
    __syncthreads();                                // buf[cur] ready
#pragma unroll
    for (int ci = 0; ci < 16; ++ci) {
      float4 x0 = *reinterpret_cast<const float4*>(&xs[cur][ci * 64 + sg * 8]);
      float4 x1 = *reinterpret_cast<const float4*>(&xs[cur][ci * 64 + sg * 8 + 4]);
      float4 w0 = *reinterpret_cast<const float4*>(&wt[cur][ci * 128 + dg * 4]);
      const float xv[8] = {x0.x, x0.y, x0.z, x0.w, x1.x, x1.y, x1.z, x1.w};
#pragma unroll
      for (int j = 0; j < 8; ++j) {
        acc[j][0] = fmaf(xv[j], w0.x, acc[j][0]);
        acc[j][1] = fmaf(xv[j], w0.y, acc[j][1]);
        acc[j][2] = fmaf(xv[j], w0.z, acc[j][2]);
        acc[j][3] = fmaf(xv[j], w0.w, acc[j][3]);
      }
    }
    cur ^= 1;
  }

  float4 bv = *reinterpret_cast<const float4*>(wv_b + dT * 128 + dg * 4);
#pragma unroll
  for (int j = 0; j < 8; ++j) {
    float4 o;
    o.x = acc[j][0] + bv.x; o.y = acc[j][1] + bv.y;
    o.z = acc[j][2] + bv.z; o.w = acc[j][3] + bv.w;
    float* dst = att_x + ((size_t)(b * SS + s0 + sg * 8 + j)) * DD + dT * 128 + dg * 4;
    *reinterpret_cast<float4*>(dst) = o;
  }
}

// ---- kernel 3 (MERGED v2): scores + softmax + out for a (b, t-quarter) block ----
// grid (64 b, 4 tq) = 256 blocks (1/CU, 16 waves), block 1024, <=128 VGPR.
// Phase A: 4 s-quarter passes; per pass thread (s=64q+(tid>>4), c=tid&15) holds
//          16 frag floats (k_score2-proven geometry) -> no respill possible.
// Softmax + Phase B: round-12-verified code.
__global__ __launch_bounds__(1024, 2) void k_score_out(
    const float* __restrict__ att_x, const float* __restrict__ att_r,
    const float* __restrict__ we_w, float* __restrict__ out, int T)
{
  const int b  = blockIdx.x;
  const int tq = blockIdx.y;
  const int tchunk = (T + 3) >> 2;      // <= 8
  const int t0 = tq * tchunk;
  const int nT = (T - t0 < tchunk) ? (T - t0) : tchunk;
  if (nT <= 0) return;
  const int tid = threadIdx.x;

  __shared__ float attrS[8 * 320];      // [tl][c*20 + j], 2-way bank alias (free)
  __shared__ float scS[8 * 256];        // scores -> alpha (in place)
  __shared__ float red[4 * 8 * 256];    // 32 KB out-reduce
  __shared__ float mred[8][4];
  __shared__ float sred[8][4];

  // ---- stage att_r*K2 (padded); zero scS ----
  for (int idx = tid; idx < nT * 256; idx += 1024) {
    int tl = idx >> 8, d = idx & 255;
    attrS[tl * 320 + (d >> 4) * 20 + (d & 15)] = att_r[(size_t)(t0 + tl) * DD + d] * K2;
  }
  for (int idx = tid; idx < 8 * 256; idx += 1024) scS[idx] = 0.f;

  const int sl = tid >> 4;       // 0..63
  const int c  = tid & 15;       // 0..15
  // we -> regs (pass-invariant)
  float4 w0, w1, w2, w3;
  {
    const float4* we4 = reinterpret_cast<const float4*>(we_w + c * 16);
    w0 = we4[0]; w1 = we4[1]; w2 = we4[2]; w3 = we4[3];
  }
  __syncthreads();

  // ---- Phase A: raw scores, 4 s-quarter passes ----
  for (int q = 0; q < 4; ++q) {
    const int s = q * 64 + sl;
    float f0x, f0y, f0z, f0w, f1x, f1y, f1z, f1w;
    float f2x, f2y, f2z, f2w, f3x, f3y, f3z, f3w;
    {
      const float4* ax4 = reinterpret_cast<const float4*>(
          att_x + ((size_t)(b * SS + s)) * DD + c * 16);
      float4 a = ax4[0], bq = ax4[1], cq = ax4[2], dq = ax4[3];
      f0x = a.x*K2;  f0y = a.y*K2;  f0z = a.z*K2;  f0w = a.w*K2;
      f1x = bq.x*K2; f1y = bq.y*K2; f1z = bq.z*K2; f1w = bq.w*K2;
      f2x = cq.x*K2; f2y = cq.y*K2; f2z = cq.z*K2; f2w = cq.w*K2;
      f3x = dq.x*K2; f3y = dq.y*K2; f3z = dq.z*K2; f3w = dq.w*K2;
    }
    for (int tl = 0; tl < nT; ++tl) {
      const float* aS = &attrS[tl * 320 + c * 20];
      float4 a0 = *reinterpret_cast<const float4*>(aS);
      float4 a1 = *reinterpret_cast<const float4*>(aS + 4);
      float4 a2 = *reinterpret_cast<const float4*>(aS + 8);
      float4 a3 = *reinterpret_cast<const float4*>(aS + 12);
      float part = 0.f;
      part = fmaf(w0.x, fast_rcp(EXP2(f0x + a0.x) + 1.f), part);
      part = fmaf(w0.y, fast_rcp(EXP2(f0y + a0.y) + 1.f), part);
      part = fmaf(w0.z, fast_rcp(EXP2(f0z + a0.z) + 1.f), part);
      part = fmaf(w0.w, fast_rcp(EXP2(f0w + a0.w) + 1.f), part);
      part = fmaf(w1.x, fast_rcp(EXP2(f1x + a1.x) + 1.f), part);
      part = fmaf(w1.y, fast_rcp(EXP2(f1y + a1.y) + 1.f), part);
      part = fmaf(w1.z, fast_rcp(EXP2(f1z + a1.z) + 1.f), part);
      part = fmaf(w1.w, fast_rcp(EXP2(f1w + a1.w) + 1.f), part);
      part = fmaf(w2.x, fast_rcp(EXP2(f2x + a2.x) + 1.f), part);
      part = fmaf(w2.y, fast_rcp(EXP2(f2y + a2.y) + 1.f), part);
      part = fmaf(w2.z, fast_rcp(EXP2(f2z + a2.z) + 1.f), part);
      part = fmaf(w2.w, fast_rcp(EXP2(f2w + a2.w) + 1.f), part);
      part = fmaf(w3.x, fast_rcp(EXP2(f3x + a3.x) + 1.f), part);
      part = fmaf(w3.y, fast_rcp(EXP2(f3y + a3.y) + 1.f), part);
      part = fmaf(w3.z, fast_rcp(EXP2(f3z + a3.z) + 1.f), part);
      part = fmaf(w3.w, fast_rcp(EXP2(f3w + a3.w) + 1.f), part);
      // reduce over c (lane bits 0..3)
      part += __shfl_xor(part, 1);
      part += __shfl_xor(part, 2);
      part += __shfl_xor(part, 4);
      part += __shfl_xor(part, 8);
      if (c == 0) scS[tl * 256 + s] = -2.f * part;  // + softmax-invariant const (dropped)
    }
  }
  __syncthreads();

  // ---- softmax over s for each live row (in LDS; round-12-verified) ----
  const int d   = tid & 255;
  const int scg = tid >> 8;   // 0..3
  const int wv4 = d >> 6;
#pragma unroll
  for (int pass = 0; pass < 2; ++pass) {
    const int r = pass * 4 + scg;       // 0..7
    const bool live = (r < nT);
    float v = live ? scS[r * 256 + d] : -3.0e38f;
    float m = v;
    m = fmaxf(m, __shfl_xor(m, 1));
    m = fmaxf(m, __shfl_xor(m, 2));
    m = fmaxf(m, __shfl_xor(m, 4));
    m = fmaxf(m, __shfl_xor(m, 8));
    m = fmaxf(m, __shfl_xor(m, 16));
    m = fmaxf(m, __shfl_xor(m, 32));
    if ((tid & 63) == 0) mred[r][wv4] = m;
    __syncthreads();
    float M = fmaxf(fmaxf(mred[r][0], mred[r][1]), fmaxf(mred[r][2], mred[r][3]));
    float ev = live ? EXP2((v - M) * LOG2E) : 0.f;
    float ss = ev;
    ss += __shfl_xor(ss, 1);
    ss += __shfl_xor(ss, 2);
    ss += __shfl_xor(ss, 4);
    ss += __shfl_xor(ss, 8);
    ss += __shfl_xor(ss, 16);
    ss += __shfl_xor(ss, 32);
    if ((tid & 63) == 0) sred[r][wv4] = ss;
    __syncthreads();
    float S = sred[r][0] + sred[r][1] + sred[r][2] + sred[r][3];
    if (live) scS[r * 256 + d] = ev * fast_rcp(S);
  }
  __syncthreads();

  // ---- Phase B: out[b][t][d] = (1/256) * sum_s alpha * att_x[b][s][d] ----
  float v[64];
  const float* ax = att_x + ((size_t)(b * SS) + scg * 64) * DD + d;
#pragma unroll
  for (int i = 0; i < 64; ++i) v[i] = ax[(size_t)i * DD];

#pragma unroll
  for (int tl = 0; tl < 8; ++tl) {
    float a = 0.f;
#pragma unroll
    for (int i4 = 0; i4 < 16; ++i4) {
      float4 a4 = *reinterpret_cast<const float4*>(&scS[tl*256 + scg*64 + i4*4]);  // wave-uniform
      a = fmaf(a4.x, v[i4*4+0], a);
      a = fmaf(a4.y, v[i4*4+1], a);
      a = fmaf(a4.z, v[i4*4+2], a);
      a = fmaf(a4.w, v[i4*4+3], a);
    }
    red[scg * 2048 + tl * 256 + d] = a;
  }
  __syncthreads();
  for (int idx = tid; idx < nT * 256; idx += 1024) {
    float sum = red[idx] + red[2048 + idx] + red[2*2048 + idx] + red[3*2048 + idx];
    out[((size_t)b * T + t0) * SS + idx] = sum * (1.0f / 256.0f);
  }
}

extern "C" void kernel_launch(void* const* d_in, const int* in_sizes, int n_in,
                              void* d_out, int out_size, void* d_ws, size_t ws_size,
                              hipStream_t stream) {
  (void)in_sizes; (void)n_in; (void)ws_size;
  const float* x    = (const float*)d_in[0];
  // d_in[1] = seq_len (device int scalar) -- T derived from out_size instead
  const float* wo_w = (const float*)d_in[2];
  const float* wo_b = (const float*)d_in[3];
  const float* wv_w = (const float*)d_in[4];
  const float* wv_b = (const float*)d_in[5];
  const float* we_w = (const float*)d_in[6];
  float* out = (float*)d_out;
  const int T = out_size / (BB * DD);

  float* att_x = (float*)d_ws;                     // 64*256*256 floats (16 MB)
  float* wvT   = att_x + (size_t)BB * SS * DD;     // 65536 floats
  float* att_r = wvT + DD * DD;                    // 64*DD reserved

  k_prep      <<<dim3(16 + T), 256, 0, stream>>>(wv_w, wo_w, wo_b, wvT, att_r, T);
  k_attx      <<<dim3(4, 2, BB), 256, 0, stream>>>(x, wvT, wv_b, att_x);
  k_score_out <<<dim3(BB, 4), 1024, 0, stream>>>(att_x, att_r, we_w, out, T);
}